// Round 4
// baseline (608.351 us; speedup 1.0000x reference)
//
#include <hip/hip_runtime.h>
#include <hip/hip_fp16.h>
#include <math.h>

// GraphSAGE mean, 2 layers. F_IN=5, F_HID=5, F_OUT=10.
// R20 = R19's sort-free aggregation, latency-fixed:
//  - agg kernels now 512 threads (24 waves/CU ceiling vs 12), stage all 18
//    edges/thread upfront (sortagg1's proven 4xint4+int2 pattern), gather
//    xh/hp in 6-deep batches (6 loads in flight/lane).
//  - LDS accumulation via unsafeAtomicAdd -> guaranteed ds_add_f32 HW atomic
//    (plain atomicAdd(float*) can lower to a CAS retry loop = R19's 99% stall).
//  - accumulator stride 6 (5 feats + inline float degree), REP=4 replicas.
// R19 post-mortem: agg1 215us, VALUBusy 1.2%, occ 19.7% -> pure dependent-
// latency stall (4-edge ILP, 8 serial iterations, 256-thr blocks), not DS
// throughput. Work content was fine (WRITE 27.4MB -> 1.95MB).
// R17 lesson kept: no grid-wide fusion (cg sync ~150us each on this runtime).

#define F_IN  5
#define F_HID 5
#define F_OUT 10

#define NBSHIFT 7                 // nodes per bucket = 128
#define NPB     (1 << NBSHIFT)    // 128
#define PBLK    1024              // partition block size
#define CHUNK   8192              // edges per partition block
#define EPT     8                 // edges per thread in partition
#define BSTRIDE 9216              // bucket stride: mean 8184 + ~11 sigma
#define SBLK    512               // agg block size (8 waves)
#define SPT     18                // staged entries/thread = BSTRIDE/SBLK
#define REP     4                 // LDS accumulator replicas
#define AST     6                 // accumulator row stride (5 feats + deg/pad)

__device__ __forceinline__ float sigmoidf(float v) {
    return 1.0f / (1.0f + __expf(-v));
}

__device__ __forceinline__ uint4 pack_h5(const float* __restrict__ xr) {
    float4 a = *(const float4*)xr;
    float a4 = xr[4];
    uint4 o;
    o.x = (unsigned)__half_as_ushort(__float2half_rn(a.x)) |
          ((unsigned)__half_as_ushort(__float2half_rn(a.y)) << 16);
    o.y = (unsigned)__half_as_ushort(__float2half_rn(a.z)) |
          ((unsigned)__half_as_ushort(__float2half_rn(a.w)) << 16);
    o.z = (unsigned)__half_as_ushort(__float2half_rn(a4));
    o.w = 0;
    return o;
}

// unpack 5 halves from a uint4 row
__device__ __forceinline__ void unp5(uint4 q, float* f) {
    float2 f01 = __half22float2(*(const __half2*)&q.x);
    float2 f23 = __half22float2(*(const __half2*)&q.y);
    float2 f45 = __half22float2(*(const __half2*)&q.z);
    f[0] = f01.x; f[1] = f01.y; f[2] = f23.x; f[3] = f23.y; f[4] = f45.x;
}

// ---- K1: partition edges by dst>>7 (cursor-first, 1 LDS atomic/edge);
//      each block also converts its 128-node slice of x to fp16 uint4 rows ----
__global__ void partition(const float* __restrict__ x,
                          const int* __restrict__ src, const int* __restrict__ dst,
                          int* __restrict__ bcursor, int* __restrict__ packed,
                          uint4* __restrict__ xh, int E, int N, int NB) {
    __shared__ int cnt[PBLK], excl[PBLK], adj[PBLK];
    __shared__ int wsum[16];
    __shared__ int buf[CHUNK];
    __shared__ unsigned char dlow[CHUNK];
    int t = threadIdx.x;
    int lane = t & 63, w = t >> 6;
    if (t < NPB) {
        int v = (blockIdx.x << NBSHIFT) + t;
        if (v < N) xh[v] = pack_h5(x + (size_t)v * 5);
    }
    cnt[t] = 0;
    __syncthreads();
    int base = blockIdx.x * CHUNK;
    int end  = min(base + CHUNK, E);
    // phase 0: vector-stage src/dst
    int sarr[EPT], darr[EPT];
    #pragma unroll
    for (int r = 0; r < 2; ++r) {
        int i = base + r * 4096 + t * 4;
        if (i + 4 <= end) {
            int4 sv = *(const int4*)(src + i);
            int4 dv = *(const int4*)(dst + i);
            sarr[r*4+0]=sv.x; sarr[r*4+1]=sv.y; sarr[r*4+2]=sv.z; sarr[r*4+3]=sv.w;
            darr[r*4+0]=dv.x; darr[r*4+1]=dv.y; darr[r*4+2]=dv.z; darr[r*4+3]=dv.w;
        } else {
            #pragma unroll
            for (int c = 0; c < 4; ++c) {
                int i2 = i + c;
                if (i2 < end) { sarr[r*4+c] = src[i2]; darr[r*4+c] = dst[i2]; }
            }
        }
    }
    // phase 1: rank via single LDS cursor atomic
    int esd[EPT];   // src | dlow<<17
    int ebp[EPT];   // b<<14 | p
    #pragma unroll
    for (int j = 0; j < EPT; ++j) {
        int i = base + (j >> 2) * 4096 + t * 4 + (j & 3);
        if (i < end) {
            int sv = sarr[j], d = darr[j];
            int b  = d >> NBSHIFT;
            int p  = atomicAdd(&cnt[b], 1);
            esd[j] = sv | ((d & (NPB - 1)) << 17);
            ebp[j] = (b << 14) | p;
        }
    }
    __syncthreads();
    // wave-shuffle inclusive scan of cnt[0..PBLK)
    int v = cnt[t];
    int incl = v;
    #pragma unroll
    for (int off = 1; off < 64; off <<= 1) {
        int u = __shfl_up(incl, off, 64);
        if (lane >= off) incl += u;
    }
    if (lane == 63) wsum[w] = incl;
    __syncthreads();
    if (t < 16) {
        int s = wsum[t];
        #pragma unroll
        for (int off = 1; off < 16; off <<= 1) {
            int u = __shfl_up(s, off, 16);
            if (t >= off) s += u;
        }
        wsum[t] = s;
    }
    __syncthreads();
    int wbase = (w > 0) ? wsum[w - 1] : 0;
    excl[t] = incl - v + wbase;
    __syncthreads();
    // reserve global space per bucket
    if (t < NB) {
        int cb = cnt[t];
        int go = cb ? atomicAdd(&bcursor[t], cb) : 0;
        adj[t] = t * BSTRIDE + go - excl[t];
    }
    __syncthreads();
    // phase 2: place from registers into LDS, bucket-grouped
    #pragma unroll
    for (int j = 0; j < EPT; ++j) {
        int i = base + (j >> 2) * 4096 + t * 4 + (j & 3);
        if (i < end) {
            int b   = ebp[j] >> 14;
            int pos = excl[b] + (ebp[j] & 0x3FFF);
            buf[pos]  = (esd[j] & 0x1FFFF) | (b << 17);
            dlow[pos] = (unsigned char)(esd[j] >> 17);
        }
    }
    __syncthreads();
    // phase 3: write runs out (consecutive pos -> same bucket -> coalesced)
    int cval = end - base;
    for (int p = t; p < cval; p += PBLK) {
        int e = buf[p];
        int b = e >> 17;
        packed[adj[b] + p] = (e & 0x1FFFF) | ((int)dlow[p] << 17);
    }
}

// ---- K2: layer-1 sort-free aggregation (HW LDS fp atomics, deep ILP) ----
__global__ void __launch_bounds__(SBLK, 6)
agg1(const uint4* __restrict__ xh, const int* __restrict__ packed,
     const int* __restrict__ bcursor,
     const float* __restrict__ Ws, const float* __restrict__ Wn,
     const float* __restrict__ bias,
     uint4* __restrict__ hp, float* __restrict__ rdeg, int N) {
    __shared__ float accf[REP * NPB * AST];   // 12,288 B
    int b = blockIdx.x, t = threadIdx.x;
    int s0  = b * BSTRIDE;
    int cnt = min(bcursor[b], BSTRIDE);
    for (int i = t; i < REP * NPB * AST; i += SBLK) accf[i] = 0.0f;
    __syncthreads();
    // stage 18 edges/thread upfront: 4 rounds int4 (16B aligned) + int2 tail
    int myv[SPT];
    #pragma unroll
    for (int r = 0; r < 4; ++r) {
        int i = r * 2048 + t * 4;
        if (i + 4 <= cnt) {
            int4 q = *(const int4*)(packed + s0 + i);
            myv[r*4+0]=q.x; myv[r*4+1]=q.y; myv[r*4+2]=q.z; myv[r*4+3]=q.w;
        } else {
            #pragma unroll
            for (int c = 0; c < 4; ++c) {
                int i2 = i + c;
                myv[r*4+c] = (i2 < cnt) ? packed[s0 + i2] : 0;
            }
        }
    }
    {
        int i = 8192 + t * 2;
        if (i + 2 <= cnt) {
            int2 q = *(const int2*)(packed + s0 + i);
            myv[16] = q.x; myv[17] = q.y;
        } else {
            myv[16] = (i     < cnt) ? packed[s0 + i]     : 0;
            myv[17] = (i + 1 < cnt) ? packed[s0 + i + 1] : 0;
        }
    }
    // gather + accumulate: 3 batches of 6 gathers in flight
    int rep = t & (REP - 1);
    #pragma unroll
    for (int batch = 0; batch < 3; ++batch) {
        uint4 g[6]; int nn[6]; bool ok[6];
        #pragma unroll
        for (int c = 0; c < 6; ++c) {
            int j = batch * 6 + c;
            int i = (j < 16) ? ((j >> 2) * 2048 + t * 4 + (j & 3))
                             : (8192 + t * 2 + (j - 16));
            int e = myv[j];
            ok[c] = (i < cnt);
            nn[c] = (e >> 17) & (NPB - 1);
            g[c] = ok[c] ? xh[e & 0x1FFFF] : make_uint4(0u, 0u, 0u, 0u);
        }
        #pragma unroll
        for (int c = 0; c < 6; ++c) {
            if (ok[c]) {
                float f[F_IN];
                unp5(g[c], f);
                float* a = accf + (rep * NPB + nn[c]) * AST;
                unsafeAtomicAdd(a + 0, f[0]);
                unsafeAtomicAdd(a + 1, f[1]);
                unsafeAtomicAdd(a + 2, f[2]);
                unsafeAtomicAdd(a + 3, f[3]);
                unsafeAtomicAdd(a + 4, f[4]);
                unsafeAtomicAdd(a + 5, 1.0f);
            }
        }
    }
    __syncthreads();
    // reduce replicas + layer-1 MLP + sigmoid -> hp (fp16x5), rdeg
    if (t < NPB) {
        int node = (b << NBSHIFT) + t;
        if (node < N) {
            float s[AST];
            #pragma unroll
            for (int f = 0; f < AST; ++f) {
                float v = 0.0f;
                #pragma unroll
                for (int r = 0; r < REP; ++r)
                    v += accf[(r * NPB + t) * AST + f];
                s[f] = v;
            }
            float rd = 1.0f / fmaxf(s[5], 1.0f);
            float ni[F_IN] = { s[0]*rd, s[1]*rd, s[2]*rd, s[3]*rd, s[4]*rd };
            float xi[F_IN];
            unp5(xh[node], xi);
            unsigned short hu[F_HID];
            #pragma unroll
            for (int j = 0; j < F_HID; ++j) {
                float acc = bias[j];
                #pragma unroll
                for (int f = 0; f < F_IN; ++f)
                    acc += xi[f] * Ws[f * F_HID + j] + ni[f] * Wn[f * F_HID + j];
                hu[j] = __half_as_ushort(__float2half_rn(sigmoidf(acc)));
            }
            uint4 o;
            o.x = (unsigned)hu[0] | ((unsigned)hu[1] << 16);
            o.y = (unsigned)hu[2] | ((unsigned)hu[3] << 16);
            o.z = (unsigned)hu[4];
            o.w = 0;
            hp[node] = o;
            rdeg[node] = rd;
        }
    }
}

// ---- K3: layer-2 sort-free aggregation, same structure over hp ----
__global__ void __launch_bounds__(SBLK, 6)
agg2(const uint4* __restrict__ hp, const int* __restrict__ packed,
     const int* __restrict__ bcursor, const float* __restrict__ rdeg,
     const float* __restrict__ Ws, const float* __restrict__ Wn,
     const float* __restrict__ bias,
     float* __restrict__ out, int N) {
    __shared__ float accf[REP * NPB * AST];
    int b = blockIdx.x, t = threadIdx.x;
    int s0  = b * BSTRIDE;
    int cnt = min(bcursor[b], BSTRIDE);
    for (int i = t; i < REP * NPB * AST; i += SBLK) accf[i] = 0.0f;
    __syncthreads();
    int myv[SPT];
    #pragma unroll
    for (int r = 0; r < 4; ++r) {
        int i = r * 2048 + t * 4;
        if (i + 4 <= cnt) {
            int4 q = *(const int4*)(packed + s0 + i);
            myv[r*4+0]=q.x; myv[r*4+1]=q.y; myv[r*4+2]=q.z; myv[r*4+3]=q.w;
        } else {
            #pragma unroll
            for (int c = 0; c < 4; ++c) {
                int i2 = i + c;
                myv[r*4+c] = (i2 < cnt) ? packed[s0 + i2] : 0;
            }
        }
    }
    {
        int i = 8192 + t * 2;
        if (i + 2 <= cnt) {
            int2 q = *(const int2*)(packed + s0 + i);
            myv[16] = q.x; myv[17] = q.y;
        } else {
            myv[16] = (i     < cnt) ? packed[s0 + i]     : 0;
            myv[17] = (i + 1 < cnt) ? packed[s0 + i + 1] : 0;
        }
    }
    int rep = t & (REP - 1);
    #pragma unroll
    for (int batch = 0; batch < 3; ++batch) {
        uint4 g[6]; int nn[6]; bool ok[6];
        #pragma unroll
        for (int c = 0; c < 6; ++c) {
            int j = batch * 6 + c;
            int i = (j < 16) ? ((j >> 2) * 2048 + t * 4 + (j & 3))
                             : (8192 + t * 2 + (j - 16));
            int e = myv[j];
            ok[c] = (i < cnt);
            nn[c] = (e >> 17) & (NPB - 1);
            g[c] = ok[c] ? hp[e & 0x1FFFF] : make_uint4(0u, 0u, 0u, 0u);
        }
        #pragma unroll
        for (int c = 0; c < 6; ++c) {
            if (ok[c]) {
                float f[F_HID];
                unp5(g[c], f);
                float* a = accf + (rep * NPB + nn[c]) * AST;
                unsafeAtomicAdd(a + 0, f[0]);
                unsafeAtomicAdd(a + 1, f[1]);
                unsafeAtomicAdd(a + 2, f[2]);
                unsafeAtomicAdd(a + 3, f[3]);
                unsafeAtomicAdd(a + 4, f[4]);
            }
        }
    }
    __syncthreads();
    if (t < NPB) {
        int node = (b << NBSHIFT) + t;
        if (node < N) {
            float s[F_HID];
            #pragma unroll
            for (int f = 0; f < F_HID; ++f) {
                float v = 0.0f;
                #pragma unroll
                for (int r = 0; r < REP; ++r)
                    v += accf[(r * NPB + t) * AST + f];
                s[f] = v;
            }
            float rd = rdeg[node];
            float ni[F_HID] = { s[0]*rd, s[1]*rd, s[2]*rd, s[3]*rd, s[4]*rd };
            float hi[F_HID];
            unp5(hp[node], hi);
            float o[F_OUT];
            #pragma unroll
            for (int j = 0; j < F_OUT; ++j) {
                float acc = bias[j];
                #pragma unroll
                for (int f = 0; f < F_HID; ++f)
                    acc += hi[f] * Ws[f * F_OUT + j] + ni[f] * Wn[f * F_OUT + j];
                o[j] = sigmoidf(acc);
            }
            float* op = out + (size_t)node * F_OUT;
            #pragma unroll
            for (int j = 0; j < F_OUT; j += 2)
                *(float2*)(op + j) = make_float2(o[j], o[j + 1]);
        }
    }
}

extern "C" void kernel_launch(void* const* d_in, const int* in_sizes, int n_in,
                              void* d_out, int out_size, void* d_ws, size_t ws_size,
                              hipStream_t stream) {
    const float* x   = (const float*)d_in[0];
    const int*   src = (const int*)d_in[1];
    const int*   dst = (const int*)d_in[2];
    const float* Ws1 = (const float*)d_in[3];
    const float* Wn1 = (const float*)d_in[4];
    const float* b1  = (const float*)d_in[5];
    const float* Ws2 = (const float*)d_in[6];
    const float* Wn2 = (const float*)d_in[7];
    const float* b2  = (const float*)d_in[8];
    float* out = (float*)d_out;

    const int N  = in_sizes[0] / F_IN;        // 100000
    const int E  = in_sizes[1];               // 6400000
    const int NB = (N + NPB - 1) >> NBSHIFT;  // 782

    // workspace (4B units):
    // bcursor[1024] | xh[4N] | rdeg[N] | packed[NB*BSTRIDE] | hp[4N]
    int*   bcursor = (int*)d_ws;
    uint4* xh      = (uint4*)(bcursor + 1024);
    float* rdeg    = (float*)(xh + N);
    int*   packed  = (int*)(rdeg + N);
    uint4* hp      = (uint4*)(packed + (size_t)NB * BSTRIDE);

    const int ablocks = (E + CHUNK - 1) / CHUNK;  // 782

    (void)hipMemsetAsync(bcursor, 0, 1024 * sizeof(int), stream);
    partition<<<ablocks, PBLK, 0, stream>>>(x, src, dst, bcursor, packed, xh, E, N, NB);
    agg1<<<NB, SBLK, 0, stream>>>(xh, packed, bcursor, Ws1, Wn1, b1, hp, rdeg, N);
    agg2<<<NB, SBLK, 0, stream>>>(hp, packed, bcursor, rdeg, Ws2, Wn2, b2, out, N);
}

// Round 5
// 207.574 us; speedup vs baseline: 2.9308x; 2.9308x over previous
//
#include <hip/hip_runtime.h>
#include <hip/hip_fp16.h>
#include <math.h>

// GraphSAGE mean, 2 layers. F_IN=5, F_HID=5, F_OUT=10.
// R21 = R18 structure (known 200us; sortagg1 42.4us all-pipes-idle,
// occ 45%) with HALVED buckets for block-level latency hiding:
//  - NBSHIFT 6 (64 nodes/bucket), BSTRIDE 4608, NB=1563.
//  - sortagg1 at 256 threads (4 waves) -> 8 blocks/CU (wave cap and LDS
//    ~18.7KB both allow 8; was 4). 1563 blocks ~= all resident at once.
//  - partition: 1024 thr unchanged; 1563 bins via pairwise scan (R17-proven);
//    adj packed into cnt to hold LDS at ~53KB.
// R19/R20 post-mortem: LDS float-atomic scatter aggregation is 5-6x WORSE
// than the counting sort (215-263us, 99% stall) regardless of ILP/occupancy
// -> DS RMW atomics are far slower than modeled. Sort-free path refuted.
// R17 lesson: no grid-wide fusion (cg grid.sync ~150us+ each here).

#define F_IN  5
#define F_HID 5
#define F_OUT 10

#define NBSHIFT 6                 // nodes per bucket = 64
#define NPB     (1 << NBSHIFT)    // 64
#define PBLK    1024              // partition block size
#define CHUNK   8192              // edges per partition block
#define EPT     8                 // edges per thread in partition
#define BSTRIDE 4608              // bucket stride: mean 4092 + ~8 sigma; 18*256
#define SBLK    256               // sortagg1 block size (4 lanes/node * 64)
#define SPT     18                // staged entries/thread = BSTRIDE/SBLK
#define LPN2    8                 // lanes per node in layer2
#define LBLK    256               // layer2 block size

__device__ __forceinline__ float sigmoidf(float v) {
    return 1.0f / (1.0f + __expf(-v));
}

__device__ __forceinline__ uint4 pack_h5(const float* __restrict__ xr) {
    float4 a = *(const float4*)xr;
    float a4 = xr[4];
    uint4 o;
    o.x = (unsigned)__half_as_ushort(__float2half_rn(a.x)) |
          ((unsigned)__half_as_ushort(__float2half_rn(a.y)) << 16);
    o.y = (unsigned)__half_as_ushort(__float2half_rn(a.z)) |
          ((unsigned)__half_as_ushort(__float2half_rn(a.w)) << 16);
    o.z = (unsigned)__half_as_ushort(__float2half_rn(a4));
    o.w = 0;
    return o;
}

__device__ __forceinline__ void acc5(uint4 q, float& a0, float& a1, float& a2,
                                     float& a3, float& a4) {
    float2 f01 = __half22float2(*(const __half2*)&q.x);
    float2 f23 = __half22float2(*(const __half2*)&q.y);
    float2 f45 = __half22float2(*(const __half2*)&q.z);
    a0 += f01.x; a1 += f01.y; a2 += f23.x; a3 += f23.y; a4 += f45.x;
}

// ---- K1: partition edges by dst>>6 (cursor-first, 1 LDS atomic/edge);
//      each block also converts a 128-node slice of x to fp16 uint4 rows ----
__global__ void partition(const float* __restrict__ x,
                          const int* __restrict__ src, const int* __restrict__ dst,
                          int* __restrict__ bcursor, int* __restrict__ packed,
                          uint4* __restrict__ xh, int E, int N, int NB) {
    __shared__ int cnt[2048];      // counts, then adj (packed in-place)
    __shared__ int excl[2048];
    __shared__ int wsum[16];
    __shared__ int buf[CHUNK];
    __shared__ unsigned char dlow[CHUNK];
    int t = threadIdx.x;
    int lane = t & 63, w = t >> 6;
    // x -> fp16 conversion: 128 nodes per block (decoupled from NBSHIFT)
    if (t < 128) {
        int v = blockIdx.x * 128 + t;
        if (v < N) xh[v] = pack_h5(x + (size_t)v * 5);
    }
    cnt[t] = 0;
    cnt[t + 1024] = 0;
    __syncthreads();
    int base = blockIdx.x * CHUNK;
    int end  = min(base + CHUNK, E);
    // phase 0: vector-stage src/dst
    int sarr[EPT], darr[EPT];
    #pragma unroll
    for (int r = 0; r < 2; ++r) {
        int i = base + r * 4096 + t * 4;
        if (i + 4 <= end) {
            int4 sv = *(const int4*)(src + i);
            int4 dv = *(const int4*)(dst + i);
            sarr[r*4+0]=sv.x; sarr[r*4+1]=sv.y; sarr[r*4+2]=sv.z; sarr[r*4+3]=sv.w;
            darr[r*4+0]=dv.x; darr[r*4+1]=dv.y; darr[r*4+2]=dv.z; darr[r*4+3]=dv.w;
        } else {
            #pragma unroll
            for (int c = 0; c < 4; ++c) {
                int i2 = i + c;
                if (i2 < end) { sarr[r*4+c] = src[i2]; darr[r*4+c] = dst[i2]; }
            }
        }
    }
    // phase 1: rank via single LDS cursor atomic
    int esd[EPT];   // src | dlow<<17   (dlow = dst & 63, 6 bits)
    int ebp[EPT];   // b<<14 | p        (b < 1563 -> 11 bits, p < 8192)
    #pragma unroll
    for (int j = 0; j < EPT; ++j) {
        int i = base + (j >> 2) * 4096 + t * 4 + (j & 3);
        if (i < end) {
            int sv = sarr[j], d = darr[j];
            int b  = d >> NBSHIFT;
            int p  = atomicAdd(&cnt[b], 1);
            esd[j] = sv | ((d & (NPB - 1)) << 17);
            ebp[j] = (b << 14) | p;
        }
    }
    __syncthreads();
    // pairwise wave-shuffle inclusive scan over NB bins (2 bins/thread)
    int c0 = (2 * t     < NB) ? cnt[2 * t]     : 0;
    int c1 = (2 * t + 1 < NB) ? cnt[2 * t + 1] : 0;
    int s = c0 + c1;
    int incl = s;
    #pragma unroll
    for (int off = 1; off < 64; off <<= 1) {
        int u = __shfl_up(incl, off, 64);
        if (lane >= off) incl += u;
    }
    if (lane == 63) wsum[w] = incl;
    __syncthreads();
    if (t < 16) {
        int sv = wsum[t];
        #pragma unroll
        for (int off = 1; off < 16; off <<= 1) {
            int u = __shfl_up(sv, off, 16);
            if (t >= off) sv += u;
        }
        wsum[t] = sv;
    }
    __syncthreads();
    int wbase = (w > 0) ? wsum[w - 1] : 0;
    int e0 = incl - s + wbase;
    if (2 * t     < NB) excl[2 * t]     = e0;
    if (2 * t + 1 < NB) excl[2 * t + 1] = e0 + c0;
    __syncthreads();
    // reserve global space per bucket; pack adj into cnt (in-place)
    for (int bb = t; bb < NB; bb += PBLK) {
        int cb = cnt[bb];
        int go = cb ? atomicAdd(&bcursor[bb], cb) : 0;
        cnt[bb] = bb * BSTRIDE + go - excl[bb];
    }
    __syncthreads();
    // phase 2: place from registers into LDS, bucket-grouped
    #pragma unroll
    for (int j = 0; j < EPT; ++j) {
        int i = base + (j >> 2) * 4096 + t * 4 + (j & 3);
        if (i < end) {
            int b   = ebp[j] >> 14;
            int pos = excl[b] + (ebp[j] & 0x3FFF);
            buf[pos]  = (esd[j] & 0x1FFFF) | (b << 17);
            dlow[pos] = (unsigned char)(esd[j] >> 17);
        }
    }
    __syncthreads();
    // phase 3: write runs out (consecutive pos -> same bucket -> coalesced)
    int cval = end - base;
    for (int p = t; p < cval; p += PBLK) {
        int e = buf[p];
        int b = e >> 17;
        packed[cnt[b] + p] = (e & 0x1FFFF) | ((int)dlow[p] << 17);
    }
}

// ---- K2: per-bucket counting sort + layer-1; 256 thr, 8 blocks/CU ----
__global__ void __launch_bounds__(SBLK, 8)
sortagg1(const uint4* __restrict__ xh, int* __restrict__ packed,
         const int* __restrict__ bcursor,
         const float* __restrict__ Ws, const float* __restrict__ Wn,
         const float* __restrict__ bias,
         uint4* __restrict__ hp, int2* __restrict__ sd, int N) {
    __shared__ int buf[BSTRIDE];           // 18,432 B
    __shared__ int ncnt[NPB], nst[NPB];
    int b = blockIdx.x, t = threadIdx.x;
    int s0  = b * BSTRIDE;
    int cnt = min(bcursor[b], BSTRIDE);
    if (t < NPB) ncnt[t] = 0;
    __syncthreads();
    // phase 0: vector-stage packed: rounds r=0..3 -> i = r*1024 + t*4 (16B
    // aligned), then tail i = 4096 + t*2 (8B aligned). Total 18/thread.
    int myv[SPT];
    #pragma unroll
    for (int r = 0; r < 4; ++r) {
        int i = r * 1024 + t * 4;
        if (i + 4 <= cnt) {
            int4 q = *(const int4*)(packed + s0 + i);
            myv[r*4+0]=q.x; myv[r*4+1]=q.y; myv[r*4+2]=q.z; myv[r*4+3]=q.w;
        } else {
            #pragma unroll
            for (int c = 0; c < 4; ++c) {
                int i2 = i + c;
                myv[r*4+c] = (i2 < cnt) ? packed[s0 + i2] : 0;
            }
        }
    }
    {
        int i = 4096 + t * 2;
        if (i + 2 <= cnt) {
            int2 q = *(const int2*)(packed + s0 + i);
            myv[16] = q.x; myv[17] = q.y;
        } else {
            myv[16] = (i     < cnt) ? packed[s0 + i]     : 0;
            myv[17] = (i + 1 < cnt) ? packed[s0 + i + 1] : 0;
        }
    }
    // phase 1: rank via single LDS cursor atomic
    short myp[SPT];
    #pragma unroll
    for (int j = 0; j < SPT; ++j) {
        int i = (j < 16) ? ((j >> 2) * 1024 + t * 4 + (j & 3)) : (4096 + t * 2 + (j - 16));
        if (i < cnt) {
            myp[j] = (short)atomicAdd(&ncnt[(myv[j] >> 17) & (NPB - 1)], 1);
        }
    }
    __syncthreads();
    // wave-shuffle exclusive scan of 64 bins (single wave)
    if (t < NPB) {
        int vv = ncnt[t];
        int incl = vv;
        #pragma unroll
        for (int off = 1; off < 64; off <<= 1) {
            int u = __shfl_up(incl, off, 64);
            if (t >= off) incl += u;
        }
        nst[t] = incl - vv;
        int node = (b << NBSHIFT) + t;
        if (node < N) sd[node] = make_int2(s0 + incl - vv, vv);
    }
    __syncthreads();
    // phase 2: place sorted into LDS from registers
    #pragma unroll
    for (int j = 0; j < SPT; ++j) {
        int i = (j < 16) ? ((j >> 2) * 1024 + t * 4 + (j & 3)) : (4096 + t * 2 + (j - 16));
        if (i < cnt) {
            int e = myv[j];
            buf[nst[(e >> 17) & (NPB - 1)] + (int)myp[j]] = e;
        }
    }
    __syncthreads();
    // phase 3: write sorted eidx back for layer2 — int4 stores
    for (int i = t * 4; i + 4 <= cnt; i += SBLK * 4) {
        int4 o = make_int4(buf[i] & 0x1FFFF, buf[i + 1] & 0x1FFFF,
                           buf[i + 2] & 0x1FFFF, buf[i + 3] & 0x1FFFF);
        *(int4*)(packed + s0 + i) = o;
    }
    {
        int tb = cnt & ~3;
        int i = tb + t;
        if (i < cnt) packed[s0 + i] = buf[i] & 0x1FFFF;
    }
    // phase 4: layer-1 aggregation from LDS, 4 lanes/node, x4-unrolled gathers
    int sub = t & 3, ln = t >> 2;          // ln in [0,64)
    int node = (b << NBSHIFT) + ln;
    float a0 = 0, a1 = 0, a2 = 0, a3 = 0, a4 = 0;
    int dg = 0;
    if (node < N) {
        int st = nst[ln];
        dg = ncnt[ln];
        int k = sub;
        for (; k + 12 < dg; k += 16) {
            int u0 = buf[st + k]      & 0x1FFFF;
            int u1 = buf[st + k + 4]  & 0x1FFFF;
            int u2 = buf[st + k + 8]  & 0x1FFFF;
            int u3 = buf[st + k + 12] & 0x1FFFF;
            uint4 q0 = xh[u0];
            uint4 q1 = xh[u1];
            uint4 q2 = xh[u2];
            uint4 q3 = xh[u3];
            acc5(q0, a0, a1, a2, a3, a4);
            acc5(q1, a0, a1, a2, a3, a4);
            acc5(q2, a0, a1, a2, a3, a4);
            acc5(q3, a0, a1, a2, a3, a4);
        }
        for (; k < dg; k += 4) {
            int u = buf[st + k] & 0x1FFFF;
            acc5(xh[u], a0, a1, a2, a3, a4);
        }
    }
    #pragma unroll
    for (int off = 2; off > 0; off >>= 1) {
        a0 += __shfl_down(a0, off, 4);
        a1 += __shfl_down(a1, off, 4);
        a2 += __shfl_down(a2, off, 4);
        a3 += __shfl_down(a3, off, 4);
        a4 += __shfl_down(a4, off, 4);
    }
    if (sub != 0 || node >= N) return;
    float rd = 1.0f / fmaxf((float)dg, 1.0f);
    float ni[F_IN] = { a0 * rd, a1 * rd, a2 * rd, a3 * rd, a4 * rd };
    uint4 qs = xh[node];
    float2 s01 = __half22float2(*(const __half2*)&qs.x);
    float2 s23 = __half22float2(*(const __half2*)&qs.y);
    float2 s45 = __half22float2(*(const __half2*)&qs.z);
    float xi[F_IN] = { s01.x, s01.y, s23.x, s23.y, s45.x };
    unsigned short hu[5];
    #pragma unroll
    for (int j = 0; j < F_HID; ++j) {
        float acc = bias[j];
        #pragma unroll
        for (int f = 0; f < F_IN; ++f)
            acc += xi[f] * Ws[f * F_HID + j] + ni[f] * Wn[f * F_HID + j];
        hu[j] = __half_as_ushort(__float2half_rn(sigmoidf(acc)));
    }
    uint4 o;
    o.x = (unsigned)hu[0] | ((unsigned)hu[1] << 16);
    o.y = (unsigned)hu[2] | ((unsigned)hu[3] << 16);
    o.z = (unsigned)hu[4];
    o.w = 0;
    hp[node] = o;
}

// ---- K3: layer 2, 8 lanes/node, contiguous k-ranges + int4 index loads ----
__global__ void layer2(const uint4* __restrict__ hp, const int* __restrict__ eidx,
                       const int2* __restrict__ sd,
                       const float* __restrict__ Ws, const float* __restrict__ Wn,
                       const float* __restrict__ b,
                       float* __restrict__ out, int N) {
    int tid = blockIdx.x * blockDim.x + threadIdx.x;
    int v   = tid >> 3;
    int sub = threadIdx.x & (LPN2 - 1);
    if (v >= N) return;
    int2 sdv = sd[v];
    int st = sdv.x, dg = sdv.y;
    int len = (dg + LPN2 - 1) >> 3;
    int k0 = sub * len;
    int k1 = min(k0 + len, dg);
    float s0 = 0, s1 = 0, s2 = 0, s3 = 0, s4 = 0;
    int k = k0;
    for (; k + 4 <= k1; k += 4) {
        int4 qi;
        __builtin_memcpy(&qi, eidx + st + k, 16);
        uint4 q0 = hp[qi.x];
        uint4 q1 = hp[qi.y];
        uint4 q2 = hp[qi.z];
        uint4 q3 = hp[qi.w];
        acc5(q0, s0, s1, s2, s3, s4);
        acc5(q1, s0, s1, s2, s3, s4);
        acc5(q2, s0, s1, s2, s3, s4);
        acc5(q3, s0, s1, s2, s3, s4);
    }
    for (; k < k1; ++k) {
        int u = eidx[st + k];
        acc5(hp[u], s0, s1, s2, s3, s4);
    }
    #pragma unroll
    for (int off = LPN2 / 2; off > 0; off >>= 1) {
        s0 += __shfl_down(s0, off, LPN2);
        s1 += __shfl_down(s1, off, LPN2);
        s2 += __shfl_down(s2, off, LPN2);
        s3 += __shfl_down(s3, off, LPN2);
        s4 += __shfl_down(s4, off, LPN2);
    }
    if (sub != 0) return;
    float rd = 1.0f / fmaxf((float)dg, 1.0f);
    float ni[F_HID] = { s0 * rd, s1 * rd, s2 * rd, s3 * rd, s4 * rd };
    uint4 q = hp[v];
    float2 f01 = __half22float2(*(const __half2*)&q.x);
    float2 f23 = __half22float2(*(const __half2*)&q.y);
    float2 f45 = __half22float2(*(const __half2*)&q.z);
    float hi[F_HID] = { f01.x, f01.y, f23.x, f23.y, f45.x };
    #pragma unroll
    for (int j = 0; j < F_OUT; ++j) {
        float acc = b[j];
        #pragma unroll
        for (int f = 0; f < F_HID; ++f)
            acc += hi[f] * Ws[f * F_OUT + j] + ni[f] * Wn[f * F_OUT + j];
        out[(size_t)v * F_OUT + j] = sigmoidf(acc);
    }
}

extern "C" void kernel_launch(void* const* d_in, const int* in_sizes, int n_in,
                              void* d_out, int out_size, void* d_ws, size_t ws_size,
                              hipStream_t stream) {
    const float* x   = (const float*)d_in[0];
    const int*   src = (const int*)d_in[1];
    const int*   dst = (const int*)d_in[2];
    const float* Ws1 = (const float*)d_in[3];
    const float* Wn1 = (const float*)d_in[4];
    const float* b1  = (const float*)d_in[5];
    const float* Ws2 = (const float*)d_in[6];
    const float* Wn2 = (const float*)d_in[7];
    const float* b2  = (const float*)d_in[8];
    float* out = (float*)d_out;

    const int N  = in_sizes[0] / F_IN;        // 100000
    const int E  = in_sizes[1];               // 6400000
    const int NB = (N + NPB - 1) >> NBSHIFT;  // 1563

    // workspace (4B units):
    // bcursor[2048] | xh[4N] | sd[2N] | packed[NB*BSTRIDE] | hp[4N]
    int*   bcursor = (int*)d_ws;
    uint4* xh      = (uint4*)(bcursor + 2048);
    int2*  sd      = (int2*)(xh + N);
    int*   packed  = (int*)(sd + N);
    uint4* hp      = (uint4*)(packed + (size_t)NB * BSTRIDE);

    const int ablocks = (E + CHUNK - 1) / CHUNK;              // 782
    const int lgrid   = ((size_t)N * LPN2 + LBLK - 1) / LBLK; // 3125

    (void)hipMemsetAsync(bcursor, 0, 2048 * sizeof(int), stream);
    partition<<<ablocks, PBLK, 0, stream>>>(x, src, dst, bcursor, packed, xh, E, N, NB);
    sortagg1<<<NB, SBLK, 0, stream>>>(xh, packed, bcursor, Ws1, Wn1, b1, hp, sd, N);
    layer2<<<lgrid, LBLK, 0, stream>>>(hp, packed, sd, Ws2, Wn2, b2, out, N);
}

// Round 6
// 202.646 us; speedup vs baseline: 3.0020x; 1.0243x over previous
//
#include <hip/hip_runtime.h>
#include <hip/hip_fp16.h>
#include <math.h>

// GraphSAGE mean, 2 layers. F_IN=5, F_HID=5, F_OUT=10.
// R22: eliminate the sorted-list round-trip. R21 evidence: fixed launch
// overhead ~70us; partition write-amp 2.1x at NB=1563 vs 1.6x at NB=782;
// sortagg1's 27MB sorted writeback + layer2's 25.6MB re-read exist ONLY to
// give layer2 contiguous per-node ranges. layer2 can re-rank in LDS itself
// (rank+scan+place ~5us) far cheaper than 51MB of HBM round-trip:
//  - partition: R16-exact (NB=782, runs ~10.5 edges, amp 1.6x).
//  - sortagg1: stage->rank->scan->place->aggregate->MLP1->hp. NO writeback,
//    NO sd array.
//  - sortagg2: same shape over hp, MLP2 -> out. (replaces layer2)
// R17: no grid-wide fusion (cg grid.sync ~150us+). R19/R20: LDS fp-atomic
// scatter refuted (5-6x worse). R18: gather ILP micro-opts neutral.

#define F_IN  5
#define F_HID 5
#define F_OUT 10

#define NBSHIFT 7                 // nodes per bucket = 128
#define NPB     (1 << NBSHIFT)    // 128
#define PBLK    1024              // partition block size
#define CHUNK   8192              // edges per partition block -> run len ~10.5
#define EPT     8                 // edges per thread in partition
#define BSTRIDE 9216              // bucket stride: mean 8184 + ~11 sigma; 18*512
#define SBLK    512               // sortagg block size (4 lanes/node * 128)
#define SPT     18                // staged entries/thread = BSTRIDE/SBLK

__device__ __forceinline__ float sigmoidf(float v) {
    return 1.0f / (1.0f + __expf(-v));
}

__device__ __forceinline__ uint4 pack_h5(const float* __restrict__ xr) {
    float4 a = *(const float4*)xr;
    float a4 = xr[4];
    uint4 o;
    o.x = (unsigned)__half_as_ushort(__float2half_rn(a.x)) |
          ((unsigned)__half_as_ushort(__float2half_rn(a.y)) << 16);
    o.y = (unsigned)__half_as_ushort(__float2half_rn(a.z)) |
          ((unsigned)__half_as_ushort(__float2half_rn(a.w)) << 16);
    o.z = (unsigned)__half_as_ushort(__float2half_rn(a4));
    o.w = 0;
    return o;
}

__device__ __forceinline__ void acc5(uint4 q, float& a0, float& a1, float& a2,
                                     float& a3, float& a4) {
    float2 f01 = __half22float2(*(const __half2*)&q.x);
    float2 f23 = __half22float2(*(const __half2*)&q.y);
    float2 f45 = __half22float2(*(const __half2*)&q.z);
    a0 += f01.x; a1 += f01.y; a2 += f23.x; a3 += f23.y; a4 += f45.x;
}

// ---- K1: partition edges by dst>>7 (cursor-first, 1 LDS atomic/edge);
//      each block also converts its 128-node slice of x to fp16 uint4 rows ----
__global__ void partition(const float* __restrict__ x,
                          const int* __restrict__ src, const int* __restrict__ dst,
                          int* __restrict__ bcursor, int* __restrict__ packed,
                          uint4* __restrict__ xh, int E, int N, int NB) {
    __shared__ int cnt[PBLK], excl[PBLK], adj[PBLK];
    __shared__ int wsum[16];
    __shared__ int buf[CHUNK];
    __shared__ unsigned char dlow[CHUNK];
    int t = threadIdx.x;
    int lane = t & 63, w = t >> 6;
    if (t < NPB) {
        int v = (blockIdx.x << NBSHIFT) + t;
        if (v < N) xh[v] = pack_h5(x + (size_t)v * 5);
    }
    cnt[t] = 0;
    __syncthreads();
    int base = blockIdx.x * CHUNK;
    int end  = min(base + CHUNK, E);
    // phase 0: vector-stage src/dst
    int sarr[EPT], darr[EPT];
    #pragma unroll
    for (int r = 0; r < 2; ++r) {
        int i = base + r * 4096 + t * 4;
        if (i + 4 <= end) {
            int4 sv = *(const int4*)(src + i);
            int4 dv = *(const int4*)(dst + i);
            sarr[r*4+0]=sv.x; sarr[r*4+1]=sv.y; sarr[r*4+2]=sv.z; sarr[r*4+3]=sv.w;
            darr[r*4+0]=dv.x; darr[r*4+1]=dv.y; darr[r*4+2]=dv.z; darr[r*4+3]=dv.w;
        } else {
            #pragma unroll
            for (int c = 0; c < 4; ++c) {
                int i2 = i + c;
                if (i2 < end) { sarr[r*4+c] = src[i2]; darr[r*4+c] = dst[i2]; }
            }
        }
    }
    // phase 1: rank via single LDS cursor atomic
    int esd[EPT];   // src | dlow<<17
    int ebp[EPT];   // b<<14 | p
    #pragma unroll
    for (int j = 0; j < EPT; ++j) {
        int i = base + (j >> 2) * 4096 + t * 4 + (j & 3);
        if (i < end) {
            int sv = sarr[j], d = darr[j];
            int b  = d >> NBSHIFT;
            int p  = atomicAdd(&cnt[b], 1);
            esd[j] = sv | ((d & (NPB - 1)) << 17);
            ebp[j] = (b << 14) | p;
        }
    }
    __syncthreads();
    // wave-shuffle inclusive scan of cnt[0..PBLK)
    int v = cnt[t];
    int incl = v;
    #pragma unroll
    for (int off = 1; off < 64; off <<= 1) {
        int u = __shfl_up(incl, off, 64);
        if (lane >= off) incl += u;
    }
    if (lane == 63) wsum[w] = incl;
    __syncthreads();
    if (t < 16) {
        int s = wsum[t];
        #pragma unroll
        for (int off = 1; off < 16; off <<= 1) {
            int u = __shfl_up(s, off, 16);
            if (t >= off) s += u;
        }
        wsum[t] = s;
    }
    __syncthreads();
    int wbase = (w > 0) ? wsum[w - 1] : 0;
    excl[t] = incl - v + wbase;
    __syncthreads();
    // reserve global space per bucket (bcursor zero-based; region = b*BSTRIDE)
    if (t < NB) {
        int cb = cnt[t];
        int go = cb ? atomicAdd(&bcursor[t], cb) : 0;
        adj[t] = t * BSTRIDE + go - excl[t];
    }
    __syncthreads();
    // phase 2: place from registers into LDS, bucket-grouped
    #pragma unroll
    for (int j = 0; j < EPT; ++j) {
        int i = base + (j >> 2) * 4096 + t * 4 + (j & 3);
        if (i < end) {
            int b   = ebp[j] >> 14;
            int pos = excl[b] + (ebp[j] & 0x3FFF);
            buf[pos]  = (esd[j] & 0x1FFFF) | (b << 17);
            dlow[pos] = (unsigned char)(esd[j] >> 17);
        }
    }
    __syncthreads();
    // phase 3: write runs out (consecutive pos -> same bucket -> coalesced)
    int cval = end - base;
    for (int p = t; p < cval; p += PBLK) {
        int e = buf[p];
        int b = e >> 17;
        packed[adj[b] + p] = (e & 0x1FFFF) | ((int)dlow[p] << 17);
    }
}

// ---- K2: per-bucket counting sort (LDS only, no writeback) + layer-1 ----
__global__ void __launch_bounds__(SBLK, 8)
sortagg1(const uint4* __restrict__ xh, const int* __restrict__ packed,
         const int* __restrict__ bcursor,
         const float* __restrict__ Ws, const float* __restrict__ Wn,
         const float* __restrict__ bias,
         uint4* __restrict__ hp, int N) {
    __shared__ int buf[BSTRIDE];
    __shared__ int ncnt[NPB], nst[NPB];
    __shared__ int w0sum;
    int b = blockIdx.x, t = threadIdx.x;
    int s0  = b * BSTRIDE;
    int cnt = min(bcursor[b], BSTRIDE);
    if (t < NPB) ncnt[t] = 0;
    __syncthreads();
    // phase 0: vector-stage packed: 4 rounds int4 + int2 tail = 18/thread
    int myv[SPT];
    #pragma unroll
    for (int r = 0; r < 4; ++r) {
        int i = r * 2048 + t * 4;
        if (i + 4 <= cnt) {
            int4 q = *(const int4*)(packed + s0 + i);
            myv[r*4+0]=q.x; myv[r*4+1]=q.y; myv[r*4+2]=q.z; myv[r*4+3]=q.w;
        } else {
            #pragma unroll
            for (int c = 0; c < 4; ++c) {
                int i2 = i + c;
                myv[r*4+c] = (i2 < cnt) ? packed[s0 + i2] : 0;
            }
        }
    }
    {
        int i = 8192 + t * 2;
        if (i + 2 <= cnt) {
            int2 q = *(const int2*)(packed + s0 + i);
            myv[16] = q.x; myv[17] = q.y;
        } else {
            myv[16] = (i     < cnt) ? packed[s0 + i]     : 0;
            myv[17] = (i + 1 < cnt) ? packed[s0 + i + 1] : 0;
        }
    }
    // phase 1: rank via single LDS cursor atomic
    short myp[SPT];
    #pragma unroll
    for (int j = 0; j < SPT; ++j) {
        int i = (j < 16) ? ((j >> 2) * 2048 + t * 4 + (j & 3)) : (8192 + t * 2 + (j - 16));
        if (i < cnt) {
            myp[j] = (short)atomicAdd(&ncnt[(myv[j] >> 17) & (NPB - 1)], 1);
        }
    }
    __syncthreads();
    // wave-shuffle exclusive scan of 128 bins
    if (t < NPB) {
        int lane = t & 63;
        int vv = ncnt[t];
        int incl = vv;
        #pragma unroll
        for (int off = 1; off < 64; off <<= 1) {
            int u = __shfl_up(incl, off, 64);
            if (lane >= off) incl += u;
        }
        if (t == 63) w0sum = incl;
        nst[t] = incl - vv;
    }
    __syncthreads();
    if (t >= 64 && t < NPB) nst[t] += w0sum;
    __syncthreads();
    // phase 2: place sorted into LDS from registers
    #pragma unroll
    for (int j = 0; j < SPT; ++j) {
        int i = (j < 16) ? ((j >> 2) * 2048 + t * 4 + (j & 3)) : (8192 + t * 2 + (j - 16));
        if (i < cnt) {
            int e = myv[j];
            buf[nst[(e >> 17) & (NPB - 1)] + (int)myp[j]] = e;
        }
    }
    __syncthreads();
    // phase 3: layer-1 aggregation from LDS, 4 lanes/node
    int sub = t & 3, ln = t >> 2;          // ln in [0,128)
    int node = (b << NBSHIFT) + ln;
    float a0 = 0, a1 = 0, a2 = 0, a3 = 0, a4 = 0;
    int dg = 0;
    if (node < N) {
        int st = nst[ln];
        dg = ncnt[ln];
        int k = sub;
        for (; k + 12 < dg; k += 16) {
            int u0 = buf[st + k]      & 0x1FFFF;
            int u1 = buf[st + k + 4]  & 0x1FFFF;
            int u2 = buf[st + k + 8]  & 0x1FFFF;
            int u3 = buf[st + k + 12] & 0x1FFFF;
            uint4 q0 = xh[u0];
            uint4 q1 = xh[u1];
            uint4 q2 = xh[u2];
            uint4 q3 = xh[u3];
            acc5(q0, a0, a1, a2, a3, a4);
            acc5(q1, a0, a1, a2, a3, a4);
            acc5(q2, a0, a1, a2, a3, a4);
            acc5(q3, a0, a1, a2, a3, a4);
        }
        for (; k < dg; k += 4) {
            int u = buf[st + k] & 0x1FFFF;
            acc5(xh[u], a0, a1, a2, a3, a4);
        }
    }
    #pragma unroll
    for (int off = 2; off > 0; off >>= 1) {
        a0 += __shfl_down(a0, off, 4);
        a1 += __shfl_down(a1, off, 4);
        a2 += __shfl_down(a2, off, 4);
        a3 += __shfl_down(a3, off, 4);
        a4 += __shfl_down(a4, off, 4);
    }
    if (sub != 0 || node >= N) return;
    float rd = 1.0f / fmaxf((float)dg, 1.0f);
    float ni[F_IN] = { a0 * rd, a1 * rd, a2 * rd, a3 * rd, a4 * rd };
    uint4 qs = xh[node];
    float2 s01 = __half22float2(*(const __half2*)&qs.x);
    float2 s23 = __half22float2(*(const __half2*)&qs.y);
    float2 s45 = __half22float2(*(const __half2*)&qs.z);
    float xi[F_IN] = { s01.x, s01.y, s23.x, s23.y, s45.x };
    unsigned short hu[5];
    #pragma unroll
    for (int j = 0; j < F_HID; ++j) {
        float acc = bias[j];
        #pragma unroll
        for (int f = 0; f < F_IN; ++f)
            acc += xi[f] * Ws[f * F_HID + j] + ni[f] * Wn[f * F_HID + j];
        hu[j] = __half_as_ushort(__float2half_rn(sigmoidf(acc)));
    }
    uint4 o;
    o.x = (unsigned)hu[0] | ((unsigned)hu[1] << 16);
    o.y = (unsigned)hu[2] | ((unsigned)hu[3] << 16);
    o.z = (unsigned)hu[4];
    o.w = 0;
    hp[node] = o;
}

// ---- K3: layer 2 as another LDS counting sort + aggregation over hp ----
__global__ void __launch_bounds__(SBLK, 8)
sortagg2(const uint4* __restrict__ hp, const int* __restrict__ packed,
         const int* __restrict__ bcursor,
         const float* __restrict__ Ws, const float* __restrict__ Wn,
         const float* __restrict__ bias,
         float* __restrict__ out, int N) {
    __shared__ int buf[BSTRIDE];
    __shared__ int ncnt[NPB], nst[NPB];
    __shared__ int w0sum;
    int b = blockIdx.x, t = threadIdx.x;
    int s0  = b * BSTRIDE;
    int cnt = min(bcursor[b], BSTRIDE);
    if (t < NPB) ncnt[t] = 0;
    __syncthreads();
    int myv[SPT];
    #pragma unroll
    for (int r = 0; r < 4; ++r) {
        int i = r * 2048 + t * 4;
        if (i + 4 <= cnt) {
            int4 q = *(const int4*)(packed + s0 + i);
            myv[r*4+0]=q.x; myv[r*4+1]=q.y; myv[r*4+2]=q.z; myv[r*4+3]=q.w;
        } else {
            #pragma unroll
            for (int c = 0; c < 4; ++c) {
                int i2 = i + c;
                myv[r*4+c] = (i2 < cnt) ? packed[s0 + i2] : 0;
            }
        }
    }
    {
        int i = 8192 + t * 2;
        if (i + 2 <= cnt) {
            int2 q = *(const int2*)(packed + s0 + i);
            myv[16] = q.x; myv[17] = q.y;
        } else {
            myv[16] = (i     < cnt) ? packed[s0 + i]     : 0;
            myv[17] = (i + 1 < cnt) ? packed[s0 + i + 1] : 0;
        }
    }
    short myp[SPT];
    #pragma unroll
    for (int j = 0; j < SPT; ++j) {
        int i = (j < 16) ? ((j >> 2) * 2048 + t * 4 + (j & 3)) : (8192 + t * 2 + (j - 16));
        if (i < cnt) {
            myp[j] = (short)atomicAdd(&ncnt[(myv[j] >> 17) & (NPB - 1)], 1);
        }
    }
    __syncthreads();
    if (t < NPB) {
        int lane = t & 63;
        int vv = ncnt[t];
        int incl = vv;
        #pragma unroll
        for (int off = 1; off < 64; off <<= 1) {
            int u = __shfl_up(incl, off, 64);
            if (lane >= off) incl += u;
        }
        if (t == 63) w0sum = incl;
        nst[t] = incl - vv;
    }
    __syncthreads();
    if (t >= 64 && t < NPB) nst[t] += w0sum;
    __syncthreads();
    #pragma unroll
    for (int j = 0; j < SPT; ++j) {
        int i = (j < 16) ? ((j >> 2) * 2048 + t * 4 + (j & 3)) : (8192 + t * 2 + (j - 16));
        if (i < cnt) {
            int e = myv[j];
            buf[nst[(e >> 17) & (NPB - 1)] + (int)myp[j]] = e;
        }
    }
    __syncthreads();
    // aggregation over hp, 4 lanes/node
    int sub = t & 3, ln = t >> 2;
    int node = (b << NBSHIFT) + ln;
    float a0 = 0, a1 = 0, a2 = 0, a3 = 0, a4 = 0;
    int dg = 0;
    if (node < N) {
        int st = nst[ln];
        dg = ncnt[ln];
        int k = sub;
        for (; k + 12 < dg; k += 16) {
            int u0 = buf[st + k]      & 0x1FFFF;
            int u1 = buf[st + k + 4]  & 0x1FFFF;
            int u2 = buf[st + k + 8]  & 0x1FFFF;
            int u3 = buf[st + k + 12] & 0x1FFFF;
            uint4 q0 = hp[u0];
            uint4 q1 = hp[u1];
            uint4 q2 = hp[u2];
            uint4 q3 = hp[u3];
            acc5(q0, a0, a1, a2, a3, a4);
            acc5(q1, a0, a1, a2, a3, a4);
            acc5(q2, a0, a1, a2, a3, a4);
            acc5(q3, a0, a1, a2, a3, a4);
        }
        for (; k < dg; k += 4) {
            int u = buf[st + k] & 0x1FFFF;
            acc5(hp[u], a0, a1, a2, a3, a4);
        }
    }
    #pragma unroll
    for (int off = 2; off > 0; off >>= 1) {
        a0 += __shfl_down(a0, off, 4);
        a1 += __shfl_down(a1, off, 4);
        a2 += __shfl_down(a2, off, 4);
        a3 += __shfl_down(a3, off, 4);
        a4 += __shfl_down(a4, off, 4);
    }
    if (sub != 0 || node >= N) return;
    float rd = 1.0f / fmaxf((float)dg, 1.0f);
    float ni[F_HID] = { a0 * rd, a1 * rd, a2 * rd, a3 * rd, a4 * rd };
    uint4 q = hp[node];
    float2 f01 = __half22float2(*(const __half2*)&q.x);
    float2 f23 = __half22float2(*(const __half2*)&q.y);
    float2 f45 = __half22float2(*(const __half2*)&q.z);
    float hi[F_HID] = { f01.x, f01.y, f23.x, f23.y, f45.x };
    float o[F_OUT];
    #pragma unroll
    for (int j = 0; j < F_OUT; ++j) {
        float acc = bias[j];
        #pragma unroll
        for (int f = 0; f < F_HID; ++f)
            acc += hi[f] * Ws[f * F_OUT + j] + ni[f] * Wn[f * F_OUT + j];
        o[j] = sigmoidf(acc);
    }
    float* op = out + (size_t)node * F_OUT;
    #pragma unroll
    for (int j = 0; j < F_OUT; j += 2)
        *(float2*)(op + j) = make_float2(o[j], o[j + 1]);
}

extern "C" void kernel_launch(void* const* d_in, const int* in_sizes, int n_in,
                              void* d_out, int out_size, void* d_ws, size_t ws_size,
                              hipStream_t stream) {
    const float* x   = (const float*)d_in[0];
    const int*   src = (const int*)d_in[1];
    const int*   dst = (const int*)d_in[2];
    const float* Ws1 = (const float*)d_in[3];
    const float* Wn1 = (const float*)d_in[4];
    const float* b1  = (const float*)d_in[5];
    const float* Ws2 = (const float*)d_in[6];
    const float* Wn2 = (const float*)d_in[7];
    const float* b2  = (const float*)d_in[8];
    float* out = (float*)d_out;

    const int N  = in_sizes[0] / F_IN;        // 100000
    const int E  = in_sizes[1];               // 6400000
    const int NB = (N + NPB - 1) >> NBSHIFT;  // 782

    // workspace (4B units):
    // bcursor[1024] (zero-based) | xh[4N] | packed[NB*BSTRIDE] | hp[4N]
    int*   bcursor = (int*)d_ws;
    uint4* xh      = (uint4*)(bcursor + 1024);
    int*   packed  = (int*)(xh + N);
    uint4* hp      = (uint4*)(packed + (size_t)NB * BSTRIDE);

    const int ablocks = (E + CHUNK - 1) / CHUNK;   // 782

    (void)hipMemsetAsync(bcursor, 0, 1024 * sizeof(int), stream);
    partition<<<ablocks, PBLK, 0, stream>>>(x, src, dst, bcursor, packed, xh, E, N, NB);
    sortagg1<<<NB, SBLK, 0, stream>>>(xh, packed, bcursor, Ws1, Wn1, b1, hp, N);
    sortagg2<<<NB, SBLK, 0, stream>>>(hp, packed, bcursor, Ws2, Wn2, b2, out, N);
}